// Round 5
// baseline (143.392 us; speedup 1.0000x reference)
//
#include <hip/hip_runtime.h>

// CRITICAL: hipcc defaults to -ffp-contract=fast-honor-pragmas, and HIP's
// __fmul_rn/__fadd_rn are PLAIN OPERATORS (not contraction barriers like
// CUDA). This pragma guarantees mul/add are not fused into v_fmac, so our
// rounding matches numpy's exactly. (R4 proved this: absmax == 0.0.)
#pragma clang fp contract(off)

// Problem constants (from reference): B=4, N=16384, M=4096, D=64
#define BB 4
#define NN 16384
#define MM 4096
#define DD 64
#define BN (BB * NN)              // 65536 points
#define FEATS_OFF 0               // feats: BN*DD floats
#define IDS_OFF (BN * DD)         // ids:   BN floats (ints stored as float)
#define PC_OFF (IDS_OFF + BN)     // pc:    BN*3 floats passthrough

#define PTS_PER_BLOCK 128         // 2 lanes per point, 256-thread block
#define KPL (MM / 2)              // 2048 keys per lane

// NUMERICS (bit-exact vs numpy fp32 replay — verified R4):
//  - cross = ((px*kx + py*ky) + pz*kz), plain rounding, no FMA.
//  - keys stored PRE-DOUBLED: (2kx,2ky,2kz,ksq). x2 is exact, so
//    cross2 = ((px*2kx + py*2ky) + pz*2kz) == 2*cross bit-exactly,
//    and d2 = (psq - cross2) + ksq == (psq - 2*cross) + ksq.
//  - p_sq/k_sq ascending plain; argmin first-index on ties.
//
// STRUCTURE (R5): 2 lanes per point; lane chunk=tid&1 scans m = 2k+chunk,
// k ascending. k is the wave-uniform loop counter -> best_k update is a
// single v_cndmask with SGPR source (no per-iter VGPR index math). The
// wave reads only 2 distinct float4s per iter (broadcast, disjoint banks).
__global__ __launch_bounds__(256, 2)
void quant_embed_kernel(const float* __restrict__ pc,
                        const float* __restrict__ keys,
                        const float* __restrict__ values,
                        float* __restrict__ out)
{
#pragma clang fp contract(off)
    __shared__ float4 skeys[MM];   // 64 KiB: (2kx, 2ky, 2kz, ksq)

    const int tid = threadIdx.x;

    // Stage all keys into LDS; k_sq in ascending-plain order; xyz doubled.
    #pragma unroll
    for (int i = 0; i < MM / 256; ++i) {
        const int m = tid + i * 256;
        const float kx = keys[3 * m + 0];
        const float ky = keys[3 * m + 1];
        const float kz = keys[3 * m + 2];
        const float ksq = ((kx * kx) + (ky * ky)) + (kz * kz);
        skeys[m] = make_float4(2.0f * kx, 2.0f * ky, 2.0f * kz, ksq);
    }

    // pc passthrough for this block's 128 points: 384 floats = 96 float4,
    // copied linearly (coalesced) by threads 0..95 while keys stage.
    {
        const int base = blockIdx.x * (PTS_PER_BLOCK * 3 / 4);  // in float4
        if (tid < PTS_PER_BLOCK * 3 / 4) {
            ((float4*)(out + PC_OFF))[base + tid] =
                ((const float4*)pc)[base + tid];
        }
    }
    __syncthreads();

    const int chunk = tid & 1;
    const int point = blockIdx.x * PTS_PER_BLOCK + (tid >> 1);

    const float px = pc[3 * point + 0];
    const float py = pc[3 * point + 1];
    const float pz = pc[3 * point + 2];
    const float psq = ((px * px) + (py * py)) + (pz * pz);

    float best_d2 = 3.402823466e38f;
    int best_k = 0;

    // Scan keys m = 2k + chunk, k ascending -> strict '<' keeps first index.
    #pragma unroll 8
    for (int k = 0; k < KPL; ++k) {
        const float4 K = skeys[(k << 1) + chunk];
        const float cross2 = ((px * K.x) + (py * K.y)) + (pz * K.z);
        const float d2 = (psq - cross2) + K.w;
        const bool lt = d2 < best_d2;
        best_d2 = lt ? d2 : best_d2;
        best_k  = lt ? k  : best_k;
    }

    int best_id = (best_k << 1) + chunk;

    // Merge across the lane pair; lexicographic (d2, id) reproduces
    // numpy's first-index tie-break exactly.
    {
        const float od = __shfl_xor(best_d2, 1);
        const int   oi = __shfl_xor(best_id, 1);
        if (od < best_d2 || (od == best_d2 && oi < best_id)) {
            best_d2 = od;
            best_id = oi;
        }
    }

    // Epilogue: the 2 lanes cooperatively copy the 64-float value row
    // (8 float4 each); lane 0 writes the id (as float).
    const float4* vrow = (const float4*)(values + (size_t)best_id * DD);
    float4* of4 = (float4*)(out + FEATS_OFF + (size_t)point * DD);
    #pragma unroll
    for (int j = 0; j < 8; ++j) {
        of4[chunk * 8 + j] = vrow[chunk * 8 + j];
    }
    if (chunk == 0) out[IDS_OFF + point] = (float)best_id;
}

extern "C" void kernel_launch(void* const* d_in, const int* in_sizes, int n_in,
                              void* d_out, int out_size, void* d_ws, size_t ws_size,
                              hipStream_t stream) {
    const float* pc     = (const float*)d_in[0];
    const float* keys   = (const float*)d_in[1];
    const float* values = (const float*)d_in[2];
    float* out = (float*)d_out;

    dim3 grid(BN / PTS_PER_BLOCK);  // 512 blocks = 2 resident blocks/CU
    dim3 block(256);
    quant_embed_kernel<<<grid, block, 0, stream>>>(pc, keys, values, out);
}

// Round 6
// 127.418 us; speedup vs baseline: 1.1254x; 1.1254x over previous
//
#include <hip/hip_runtime.h>

// CRITICAL: hipcc defaults to -ffp-contract=fast-honor-pragmas, and HIP's
// __fmul_rn/__fadd_rn are PLAIN OPERATORS (not contraction barriers like
// CUDA). This pragma guarantees mul/add are not fused into v_fmac, so our
// rounding matches numpy's exactly. (R4 proved this: absmax == 0.0.)
#pragma clang fp contract(off)

// Problem constants (from reference): B=4, N=16384, M=4096, D=64
#define BB 4
#define NN 16384
#define MM 4096
#define DD 64
#define BN (BB * NN)              // 65536 points
#define FEATS_OFF 0               // feats: BN*DD floats
#define IDS_OFF (BN * DD)         // ids:   BN floats (ints stored as float)
#define PC_OFF (IDS_OFF + BN)     // pc:    BN*3 floats passthrough

#define CC 8                      // key-split: lanes per point
#define PP 4                      // points per thread (register tile)
#define PPB (256 * PP / CC)       // 128 points per block
#define KPL (MM / CC)             // 512 keys per lane

// NUMERICS (bit-exact vs numpy fp32 replay — verified R4/R5):
//  - keys PRE-DOUBLED in LDS: (2kx,2ky,2kz,ksq); x2 exact =>
//    d2 = (psq - ((px*2kx + py*2ky) + pz*2kz)) + ksq == reference bits.
//  - all plain rn (contract off), p_sq/k_sq ascending plain.
//  - argmin: per-chunk ascending scan, strict '<', lexicographic (d2,id)
//    butterfly => numpy first-index tie-break.
//
// STRUCTURE (R6): LDS issue was the R4/R5 bottleneck (1 ds_read_b128 per
// eval-pair; LDS pipe is per-CU). Register-tile PP=4 points per thread so
// each key read serves 4 evals: LDS ~20 us < VALU floor ~34 us. The 4
// independent d2 chains also hide ds latency at 2 waves/SIMD.
__global__ __launch_bounds__(256, 2)
void quant_embed_kernel(const float* __restrict__ pc,
                        const float* __restrict__ keys,
                        const float* __restrict__ values,
                        float* __restrict__ out)
{
#pragma clang fp contract(off)
    __shared__ float4 skeys[MM];   // 64 KiB: (2kx, 2ky, 2kz, ksq)

    const int tid = threadIdx.x;

    // Stage all keys into LDS; k_sq ascending-plain; xyz doubled (exact).
    #pragma unroll
    for (int i = 0; i < MM / 256; ++i) {
        const int m = tid + i * 256;
        const float kx = keys[3 * m + 0];
        const float ky = keys[3 * m + 1];
        const float kz = keys[3 * m + 2];
        const float ksq = ((kx * kx) + (ky * ky)) + (kz * kz);
        skeys[m] = make_float4(2.0f * kx, 2.0f * ky, 2.0f * kz, ksq);
    }

    // pc passthrough for this block's 128 points: 384 floats = 96 float4.
    {
        const int base = blockIdx.x * (PPB * 3 / 4);  // in float4
        if (tid < PPB * 3 / 4) {
            ((float4*)(out + PC_OFF))[base + tid] =
                ((const float4*)pc)[base + tid];
        }
    }

    const int chunk = tid & (CC - 1);
    const int g = tid >> 3;                       // point-group 0..31
    const int p0 = blockIdx.x * PPB + g * PP;     // my first point

    float px[PP], py[PP], pz[PP], psq[PP], bd[PP];
    int bk[PP];
    #pragma unroll
    for (int i = 0; i < PP; ++i) {
        px[i] = pc[3 * (p0 + i) + 0];
        py[i] = pc[3 * (p0 + i) + 1];
        pz[i] = pc[3 * (p0 + i) + 2];
        psq[i] = ((px[i] * px[i]) + (py[i] * py[i])) + (pz[i] * pz[i]);
        bd[i] = 3.402823466e38f;
        bk[i] = 0;
    }

    __syncthreads();

    // Scan keys m = 8k + chunk, k ascending -> strict '<' keeps first index
    // within the chunk. One ds_read_b128 serves PP=4 evals.
    #pragma unroll 4
    for (int k = 0; k < KPL; ++k) {
        const float4 K = skeys[(k << 3) + chunk];
        #pragma unroll
        for (int i = 0; i < PP; ++i) {
            const float cross2 = ((px[i] * K.x) + (py[i] * K.y)) + (pz[i] * K.z);
            const float d2 = (psq[i] - cross2) + K.w;
            const bool lt = d2 < bd[i];
            bd[i] = lt ? d2 : bd[i];
            bk[i] = lt ? k  : bk[i];
        }
    }

    // Per point: merge the 8 chunk-lanes (butterfly, lexicographic (d2,id)
    // => numpy first-index tie-break). All 8 lanes end with the winner.
    int bid[PP];
    #pragma unroll
    for (int i = 0; i < PP; ++i) {
        float d = bd[i];
        int   m = (bk[i] << 3) + chunk;
        #pragma unroll
        for (int off = 1; off <= 4; off <<= 1) {
            const float od = __shfl_xor(d, off);
            const int   om = __shfl_xor(m, off);
            if (od < d || (od == d && om < m)) { d = od; m = om; }
        }
        bid[i] = m;
    }

    // Epilogue: each point's 8 lanes copy its 64-float value row (2 float4
    // per lane => coalesced 16B/lane); chunk 0 writes ids (as float).
    #pragma unroll
    for (int i = 0; i < PP; ++i) {
        const float4* vrow = (const float4*)(values + (size_t)bid[i] * DD);
        float4* of4 = (float4*)(out + FEATS_OFF + (size_t)(p0 + i) * DD);
        of4[chunk * 2 + 0] = vrow[chunk * 2 + 0];
        of4[chunk * 2 + 1] = vrow[chunk * 2 + 1];
        if (chunk == 0) out[IDS_OFF + p0 + i] = (float)bid[i];
    }
}

extern "C" void kernel_launch(void* const* d_in, const int* in_sizes, int n_in,
                              void* d_out, int out_size, void* d_ws, size_t ws_size,
                              hipStream_t stream) {
    const float* pc     = (const float*)d_in[0];
    const float* keys   = (const float*)d_in[1];
    const float* values = (const float*)d_in[2];
    float* out = (float*)d_out;

    dim3 grid(BN / PPB);  // 512 blocks = 2 resident blocks/CU
    dim3 block(256);
    quant_embed_kernel<<<grid, block, 0, stream>>>(pc, keys, values, out);
}

// Round 7
// 125.809 us; speedup vs baseline: 1.1398x; 1.0128x over previous
//
#include <hip/hip_runtime.h>

// CRITICAL: hipcc defaults to -ffp-contract=fast-honor-pragmas, and HIP's
// __fmul_rn/__fadd_rn are PLAIN OPERATORS (not contraction barriers like
// CUDA). This pragma guarantees mul/add are not fused into v_fmac, so our
// rounding matches numpy's exactly. (R4 proved this: absmax == 0.0.)
#pragma clang fp contract(off)

// Problem constants (from reference): B=4, N=16384, M=4096, D=64
#define MM 4096
#define DD 64
#define BN 65536                  // B*N points
#define FEATS_OFF 0               // feats: BN*DD floats
#define IDS_OFF (BN * DD)         // ids:   BN floats (ints stored as float)
#define PC_OFF (IDS_OFF + BN)     // pc:    BN*3 floats passthrough

#define CC 16                     // lanes per point
#define PP 8                      // points per thread (register tile)
#define PPB 128                   // points per block (256*PP/CC)
#define NPAIR (MM / 2)            // 2048 key pairs
#define KIT (MM / (2 * CC))       // 128 main-loop iterations

// NUMERICS (bit-exact vs numpy fp32 replay — verified R4/R5/R6):
//  - keys PRE-DOUBLED: x2 exact => d2 = (psq - ((px*2kx + py*2ky) + pz*2kz))
//    + ksq == reference bits; all plain rn (contract off); k_sq/p_sq
//    ascending plain; per-lane scan in ascending m order (pair a then b),
//    strict '<' + lexicographic (d2,id) butterfly => first-index tie-break.
//
// STRUCTURE (R7): CC=16 x PP=8, two keys per iteration from component-paired
// SoA LDS (skA: x/y pairs, skB: z/ksq pairs). One iteration = 2 ds_read_b128
// serving 16 evals -> per-iter overhead ~0.4 instr/eval (was ~5 in R6), LDS
// issue ~10 us/CU (hidden under ~36 us VALU).
__global__ __launch_bounds__(256, 2)
void quant_embed_kernel(const float* __restrict__ pc,
                        const float* __restrict__ keys,
                        const float* __restrict__ values,
                        float* __restrict__ out)
{
#pragma clang fp contract(off)
    __shared__ float4 skA[NPAIR];  // (2kx_e, 2kx_o, 2ky_e, 2ky_o)  32 KiB
    __shared__ float4 skB[NPAIR];  // (2kz_e, 2kz_o, ksq_e, ksq_o)  32 KiB

    const int tid = threadIdx.x;

    // Stage key pairs: thread t handles pairs j = t + 256*i (8 pairs).
    // Pair j = keys 2j (f0.x,f0.y,f1.x) and 2j+1 (f1.y,f2.x,f2.y).
    #pragma unroll
    for (int i = 0; i < NPAIR / 256; ++i) {
        const int j = tid + i * 256;
        const float2 f0 = ((const float2*)keys)[3 * j + 0];
        const float2 f1 = ((const float2*)keys)[3 * j + 1];
        const float2 f2 = ((const float2*)keys)[3 * j + 2];
        const float ksq0 = ((f0.x * f0.x) + (f0.y * f0.y)) + (f1.x * f1.x);
        const float ksq1 = ((f1.y * f1.y) + (f2.x * f2.x)) + (f2.y * f2.y);
        skA[j] = make_float4(2.0f * f0.x, 2.0f * f1.y, 2.0f * f0.y, 2.0f * f2.x);
        skB[j] = make_float4(2.0f * f1.x, 2.0f * f2.y, ksq0, ksq1);
    }

    // pc passthrough for this block's 128 points: 384 floats = 96 float4.
    {
        const int base = blockIdx.x * (PPB * 3 / 4);  // in float4
        if (tid < PPB * 3 / 4) {
            ((float4*)(out + PC_OFF))[base + tid] =
                ((const float4*)pc)[base + tid];
        }
    }

    const int c = tid & (CC - 1);
    const int g = tid >> 4;                       // point-group 0..15
    const int p0 = blockIdx.x * PPB + g * PP;     // my first point

    // Load my 8 points (24 floats = 6 float4, aligned since 3*p0 % 4 == 0).
    float arr[24];
    {
        const float4* pcv = (const float4*)(pc + 3 * p0);
        #pragma unroll
        for (int i = 0; i < 6; ++i) ((float4*)arr)[i] = pcv[i];
    }
    float px[PP], py[PP], pz[PP], psq[PP], bd[PP];
    int bm[PP];
    #pragma unroll
    for (int i = 0; i < PP; ++i) {
        px[i] = arr[3 * i + 0];
        py[i] = arr[3 * i + 1];
        pz[i] = arr[3 * i + 2];
        psq[i] = ((px[i] * px[i]) + (py[i] * py[i])) + (pz[i] * pz[i]);
        bd[i] = 3.402823466e38f;
        bm[i] = 0;
    }

    __syncthreads();

    // Main loop: lane c, iter k handles pair j = 16k + c, i.e. keys
    // m0 = 32k + 2c and m0+1. a-then-b preserves ascending index order.
    #pragma unroll 2
    for (int k = 0; k < KIT; ++k) {
        const int j = (k << 4) + c;
        const float4 A  = skA[j];
        const float4 Bv = skB[j];
        const int m0 = (k << 5) + (c << 1);
        const int m1 = m0 + 1;
        #pragma unroll
        for (int i = 0; i < PP; ++i) {
            const float ca = ((px[i] * A.x) + (py[i] * A.z)) + (pz[i] * Bv.x);
            const float da = (psq[i] - ca) + Bv.z;
            const bool lta = da < bd[i];
            bd[i] = lta ? da : bd[i];
            bm[i] = lta ? m0 : bm[i];
            const float cb = ((px[i] * A.y) + (py[i] * A.w)) + (pz[i] * Bv.y);
            const float db = (psq[i] - cb) + Bv.w;
            const bool ltb = db < bd[i];
            bd[i] = ltb ? db : bd[i];
            bm[i] = ltb ? m1 : bm[i];
        }
    }

    // Merge the 16 chunk lanes per point (butterfly, lexicographic (d2,id)
    // => numpy first-index tie-break). All lanes end with the winner.
    #pragma unroll
    for (int i = 0; i < PP; ++i) {
        float d = bd[i];
        int   m = bm[i];
        #pragma unroll
        for (int off = 1; off < CC; off <<= 1) {
            const float od = __shfl_xor(d, off);
            const int   om = __shfl_xor(m, off);
            if (od < d || (od == d && om < m)) { d = od; m = om; }
        }
        bm[i] = m;
    }

    // Epilogue: each point's 16 lanes copy its 64-float value row
    // (1 float4 per lane, coalesced 256B); lane c==0 writes the id.
    #pragma unroll
    for (int i = 0; i < PP; ++i) {
        const float4* vrow = (const float4*)(values + (size_t)bm[i] * DD);
        ((float4*)(out + FEATS_OFF + (size_t)(p0 + i) * DD))[c] = vrow[c];
        if (c == 0) out[IDS_OFF + p0 + i] = (float)bm[i];
    }
}

extern "C" void kernel_launch(void* const* d_in, const int* in_sizes, int n_in,
                              void* d_out, int out_size, void* d_ws, size_t ws_size,
                              hipStream_t stream) {
    const float* pc     = (const float*)d_in[0];
    const float* keys   = (const float*)d_in[1];
    const float* values = (const float*)d_in[2];
    float* out = (float*)d_out;

    dim3 grid(BN / PPB);  // 512 blocks = 2 resident blocks/CU
    dim3 block(256);
    quant_embed_kernel<<<grid, block, 0, stream>>>(pc, keys, values, out);
}

// Round 8
// 120.919 us; speedup vs baseline: 1.1859x; 1.0404x over previous
//
#include <hip/hip_runtime.h>

// CRITICAL: hipcc defaults to -ffp-contract=fast-honor-pragmas, and HIP's
// __fmul_rn/__fadd_rn are PLAIN OPERATORS (not contraction barriers like
// CUDA). This pragma guarantees mul/add are not fused into v_fmac/v_pk_fma,
// so our rounding matches numpy's exactly. (R4 proved this: absmax == 0.0.)
#pragma clang fp contract(off)

typedef float v2f __attribute__((ext_vector_type(2)));

// Problem constants (from reference): B=4, N=16384, M=4096, D=64
#define MM 4096
#define DD 64
#define BN 65536                  // B*N points
#define FEATS_OFF 0               // feats: BN*DD floats
#define IDS_OFF (BN * DD)         // ids:   BN floats (ints stored as float)
#define PC_OFF (IDS_OFF + BN)     // pc:    BN*3 floats passthrough

#define BLK 512                   // threads per block (8 waves)
#define CC 32                     // lanes per point
#define PP 8                      // points per thread (register tile)
#define PPB 128                   // points per block (BLK*PP/CC)
#define NPAIR (MM / 2)            // 2048 key pairs
#define KIT (MM / (2 * CC))       // 64 main-loop iterations

// NUMERICS (bit-exact vs numpy fp32 replay — verified R4-R7):
//  - keys PRE-DOUBLED: x2 exact => d2 = (psq - ((px*2kx + py*2ky) + pz*2kz))
//    + ksq == reference bits; all plain rn (contract off); k_sq/p_sq
//    ascending plain. v_pk_mul/v_pk_add are per-component plain rn ==
//    scalar bits; contract(off) forbids pk_fma formation.
//  - argmin: per-lane ascending m (pair a then b), strict '<',
//    lexicographic (d2,id) butterfly => numpy first-index tie-break.
//
// STRUCTURE (R8): R6/R7 showed the binding constraint was 2 waves/SIMD
// (64 KiB LDS + 256-thread block => 8 waves/CU) — ds latency unhidden
// (VALUBusy ~71%). Fix: 512-thread block => 2 blocks/CU x 8 waves = 4
// waves/SIMD, same 64 KiB LDS, no restaging. Plus float2 packed math so
// the backend can emit v_pk_*_f32 (~6.5 instr/eval vs 10).
__global__ __launch_bounds__(BLK, 4)
void quant_embed_kernel(const float* __restrict__ pc,
                        const float* __restrict__ keys,
                        const float* __restrict__ values,
                        float* __restrict__ out)
{
#pragma clang fp contract(off)
    __shared__ float4 skA[NPAIR];  // (2kx_e, 2kx_o, 2ky_e, 2ky_o)  32 KiB
    __shared__ float4 skB[NPAIR];  // (2kz_e, 2kz_o, ksq_e, ksq_o)  32 KiB

    const int tid = threadIdx.x;

    // Stage key pairs: thread t handles pairs j = t + BLK*i (4 pairs).
    // Pair j = keys 2j (f0.x,f0.y,f1.x) and 2j+1 (f1.y,f2.x,f2.y).
    #pragma unroll
    for (int i = 0; i < NPAIR / BLK; ++i) {
        const int j = tid + i * BLK;
        const float2 f0 = ((const float2*)keys)[3 * j + 0];
        const float2 f1 = ((const float2*)keys)[3 * j + 1];
        const float2 f2 = ((const float2*)keys)[3 * j + 2];
        const float ksq0 = ((f0.x * f0.x) + (f0.y * f0.y)) + (f1.x * f1.x);
        const float ksq1 = ((f1.y * f1.y) + (f2.x * f2.x)) + (f2.y * f2.y);
        skA[j] = make_float4(2.0f * f0.x, 2.0f * f1.y, 2.0f * f0.y, 2.0f * f2.x);
        skB[j] = make_float4(2.0f * f1.x, 2.0f * f2.y, ksq0, ksq1);
    }

    // pc passthrough for this block's 128 points: 384 floats = 96 float4.
    {
        const int base = blockIdx.x * (PPB * 3 / 4);  // in float4
        if (tid < PPB * 3 / 4) {
            ((float4*)(out + PC_OFF))[base + tid] =
                ((const float4*)pc)[base + tid];
        }
    }

    const int c = tid & (CC - 1);
    const int g = tid >> 5;                       // point-group 0..15
    const int p0 = blockIdx.x * PPB + g * PP;     // my first point

    // Load my 8 points (24 floats = 6 float4, aligned: 3*p0 % 4 == 0).
    float arr[24];
    {
        const float4* pcv = (const float4*)(pc + 3 * p0);
        #pragma unroll
        for (int i = 0; i < 6; ++i) ((float4*)arr)[i] = pcv[i];
    }
    float px[PP], py[PP], pz[PP], psq[PP], bd[PP];
    int bm[PP];
    #pragma unroll
    for (int i = 0; i < PP; ++i) {
        px[i] = arr[3 * i + 0];
        py[i] = arr[3 * i + 1];
        pz[i] = arr[3 * i + 2];
        psq[i] = ((px[i] * px[i]) + (py[i] * py[i])) + (pz[i] * pz[i]);
        bd[i] = 3.402823466e38f;
        bm[i] = 0;
    }

    __syncthreads();

    // Main loop: lane c, iter k handles pair j = 32k + c, i.e. keys
    // m0 = 64k + 2c and m0+1. a-then-b preserves ascending index order.
    #pragma unroll 2
    for (int k = 0; k < KIT; ++k) {
        const int j = (k << 5) + c;
        const float4 A  = skA[j];
        const float4 Bv = skB[j];
        const v2f Kx = {A.x,  A.y};    // 2kx even/odd
        const v2f Ky = {A.z,  A.w};    // 2ky even/odd
        const v2f Kz = {Bv.x, Bv.y};   // 2kz even/odd
        const v2f Ks = {Bv.z, Bv.w};   // ksq even/odd
        const int m0 = (k << 6) + (c << 1);
        const int m1 = m0 + 1;
        #pragma unroll
        for (int i = 0; i < PP; ++i) {
            const v2f tx = Kx * px[i];
            const v2f ty = Ky * py[i];
            const v2f tz = Kz * pz[i];
            const v2f s  = tx + ty;
            const v2f s2 = s + tz;
            const v2f d  = psq[i] - s2;
            const v2f d2 = d + Ks;
            const float da = d2.x;
            const bool lta = da < bd[i];
            bd[i] = lta ? da : bd[i];
            bm[i] = lta ? m0 : bm[i];
            const float db = d2.y;
            const bool ltb = db < bd[i];
            bd[i] = ltb ? db : bd[i];
            bm[i] = ltb ? m1 : bm[i];
        }
    }

    // Merge the 32 chunk lanes per point (butterfly, lexicographic (d2,id)
    // => numpy first-index tie-break). All lanes end with the winner.
    #pragma unroll
    for (int i = 0; i < PP; ++i) {
        float d = bd[i];
        int   m = bm[i];
        #pragma unroll
        for (int off = 1; off < CC; off <<= 1) {
            const float od = __shfl_xor(d, off);
            const int   om = __shfl_xor(m, off);
            if (od < d || (od == d && om < m)) { d = od; m = om; }
        }
        bm[i] = m;
    }

    // Epilogue: each point's 32 lanes copy its 64-float value row
    // (1 float2 per lane, coalesced 256B); lane c==0 writes the id.
    #pragma unroll
    for (int i = 0; i < PP; ++i) {
        const float2* vrow = (const float2*)(values + (size_t)bm[i] * DD);
        ((float2*)(out + FEATS_OFF + (size_t)(p0 + i) * DD))[c] = vrow[c];
        if (c == 0) out[IDS_OFF + p0 + i] = (float)bm[i];
    }
}

extern "C" void kernel_launch(void* const* d_in, const int* in_sizes, int n_in,
                              void* d_out, int out_size, void* d_ws, size_t ws_size,
                              hipStream_t stream) {
    const float* pc     = (const float*)d_in[0];
    const float* keys   = (const float*)d_in[1];
    const float* values = (const float*)d_in[2];
    float* out = (float*)d_out;

    dim3 grid(BN / PPB);  // 512 blocks of 512 threads = 2 blocks/CU
    dim3 block(BLK);
    quant_embed_kernel<<<grid, block, 0, stream>>>(pc, keys, values, out);
}

// Round 9
// 111.344 us; speedup vs baseline: 1.2878x; 1.0860x over previous
//
#include <hip/hip_runtime.h>

// CRITICAL: hipcc defaults to -ffp-contract=fast-honor-pragmas, and HIP's
// __fmul_rn/__fadd_rn are PLAIN OPERATORS (not contraction barriers like
// CUDA). This pragma guarantees mul/add are not fused into v_fmac/v_pk_fma,
// so our rounding matches numpy's exactly. (R4 proved this: absmax == 0.0.)
#pragma clang fp contract(off)

typedef float v2f __attribute__((ext_vector_type(2)));

// Forced packed fp32 (VOP3P): per-component rounding == scalar v_mul/v_add.
static __device__ __forceinline__ v2f pk_mul(v2f a, v2f b) {
    v2f d;
    asm("v_pk_mul_f32 %0, %1, %2" : "=v"(d) : "v"(a), "v"(b));
    return d;
}
static __device__ __forceinline__ v2f pk_add(v2f a, v2f b) {
    v2f d;
    asm("v_pk_add_f32 %0, %1, %2" : "=v"(d) : "v"(a), "v"(b));
    return d;
}
static __device__ __forceinline__ float min3f(float a, float b, float c) {
    float d;
    asm("v_min3_f32 %0, %1, %2, %3" : "=v"(d) : "v"(a), "v"(b), "v"(c));
    return d;
}

// Problem constants (from reference): B=4, N=16384, M=4096, D=64
#define MM 4096
#define DD 64
#define BN 65536                  // B*N points
#define FEATS_OFF 0               // feats: BN*DD floats
#define IDS_OFF (BN * DD)         // ids:   BN floats (ints stored as float)
#define PC_OFF (IDS_OFF + BN)     // pc:    BN*3 floats passthrough

#define BLK 512                   // threads per block (8 waves)
#define CC 32                     // lanes per point
#define PP 8                      // points per thread (register tile)
#define PPB 128                   // points per block (BLK*PP/CC)
#define NPAIR (MM / 2)            // 2048 key pairs
#define KIT (MM / (2 * CC))       // 64 main-loop iterations

// NUMERICS (bit-exact vs numpy fp32 replay — verified R4-R8):
//  - keys stored NEGATED+DOUBLED: rn commutes with sign and 2^k scaling, so
//    cross' = ((px*(-2kx) + py*(-2ky)) + pz*(-2kz)) == -2*cross bit-exact,
//    and d2 = (psq + cross') + ksq == (psq - 2*cross) + ksq == ref bits.
//  - all plain rn (contract off); k_sq/p_sq ascending plain; pk per-lane
//    rounding == scalar.
//  - argmin: bd via v_min3 (== sequential strict-'<' min, no NaNs); bk =
//    first iter where bd strictly dropped (later equal values don't
//    overwrite => first-index kept); within-pair even preferred on tie at
//    recovery; lexicographic (d2,id) butterfly across lanes.
//
// STRUCTURE (R9): R8 counters showed the backend scalarized float2 math
// (~14.7 instr/eval). Force v_pk_* via asm + min3/deferred-index
// bookkeeping: 10 issue slots per key-pair = 5/eval.
__global__ __launch_bounds__(BLK, 4)
void quant_embed_kernel(const float* __restrict__ pc,
                        const float* __restrict__ keys,
                        const float* __restrict__ values,
                        float* __restrict__ out)
{
#pragma clang fp contract(off)
    __shared__ float4 skA[NPAIR];  // (-2kx_e, -2kx_o, -2ky_e, -2ky_o) 32 KiB
    __shared__ float4 skB[NPAIR];  // (-2kz_e, -2kz_o,  ksq_e,  ksq_o) 32 KiB

    const int tid = threadIdx.x;

    // Stage key pairs: pair j = keys 2j (f0.x,f0.y,f1.x), 2j+1 (f1.y,f2.x,f2.y).
    #pragma unroll
    for (int i = 0; i < NPAIR / BLK; ++i) {
        const int j = tid + i * BLK;
        const float2 f0 = ((const float2*)keys)[3 * j + 0];
        const float2 f1 = ((const float2*)keys)[3 * j + 1];
        const float2 f2 = ((const float2*)keys)[3 * j + 2];
        const float ksq0 = ((f0.x * f0.x) + (f0.y * f0.y)) + (f1.x * f1.x);
        const float ksq1 = ((f1.y * f1.y) + (f2.x * f2.x)) + (f2.y * f2.y);
        skA[j] = make_float4(-2.0f * f0.x, -2.0f * f1.y,
                             -2.0f * f0.y, -2.0f * f2.x);
        skB[j] = make_float4(-2.0f * f1.x, -2.0f * f2.y, ksq0, ksq1);
    }

    // pc passthrough for this block's 128 points: 384 floats = 96 float4.
    {
        const int base = blockIdx.x * (PPB * 3 / 4);  // in float4
        if (tid < PPB * 3 / 4) {
            ((float4*)(out + PC_OFF))[base + tid] =
                ((const float4*)pc)[base + tid];
        }
    }

    const int c = tid & (CC - 1);
    const int g = tid >> 5;                       // point-group 0..15
    const int p0 = blockIdx.x * PPB + g * PP;     // my first point

    // Load my 8 points (24 floats = 6 float4, aligned: 3*p0 % 4 == 0).
    float arr[24];
    {
        const float4* pcv = (const float4*)(pc + 3 * p0);
        #pragma unroll
        for (int i = 0; i < 6; ++i) ((float4*)arr)[i] = pcv[i];
    }
    v2f PX[PP], PY[PP], PZ[PP], PSQ[PP];
    float bd[PP];
    int bk[PP];
    #pragma unroll
    for (int i = 0; i < PP; ++i) {
        const float px = arr[3 * i + 0];
        const float py = arr[3 * i + 1];
        const float pz = arr[3 * i + 2];
        const float psq = ((px * px) + (py * py)) + (pz * pz);
        PX[i] = (v2f){px, px};
        PY[i] = (v2f){py, py};
        PZ[i] = (v2f){pz, pz};
        PSQ[i] = (v2f){psq, psq};
        bd[i] = 3.402823466e38f;
        bk[i] = 0;
    }

    __syncthreads();

    // Main loop: lane c, iter k handles pair j = 32k + c (keys 64k+2c, +1).
    // Per pair per point: 7 pk + min3 + cmp + cndmask = 10 slots / 2 evals.
    #pragma unroll 2
    for (int k = 0; k < KIT; ++k) {
        const int j = (k << 5) + c;
        const float4 A  = skA[j];
        const float4 Bv = skB[j];
        const v2f Kx = {A.x,  A.y};
        const v2f Ky = {A.z,  A.w};
        const v2f Kz = {Bv.x, Bv.y};
        const v2f Ks = {Bv.z, Bv.w};
        #pragma unroll
        for (int i = 0; i < PP; ++i) {
            v2f t = pk_add(pk_mul(Kx, PX[i]), pk_mul(Ky, PY[i]));
            t = pk_add(t, pk_mul(Kz, PZ[i]));
            t = pk_add(PSQ[i], t);       // psq - 2*cross (keys negated)
            t = pk_add(t, Ks);           // + ksq
            const float nb = min3f(bd[i], t.x, t.y);
            const bool ch = nb < bd[i];  // strict drop => first-index kept
            bd[i] = nb;
            bk[i] = ch ? k : bk[i];
        }
    }

    // Recover the winning key within pair bk[i] (scalar plain == pk bits),
    // then merge the 32 lanes (lexicographic (d2,id) butterfly).
    int bm[PP];
    #pragma unroll
    for (int i = 0; i < PP; ++i) {
        const int j = (bk[i] << 5) + c;
        const float4 A  = skA[j];
        const float4 Bv = skB[j];
        const float ca = ((PX[i].x * A.x) + (PY[i].x * A.z)) + (PZ[i].x * Bv.x);
        const float da = (PSQ[i].x + ca) + Bv.z;
        const int m0 = (bk[i] << 6) + (c << 1);
        float d = bd[i];
        int   m = (da == bd[i]) ? m0 : (m0 + 1);  // even preferred on tie
        #pragma unroll
        for (int off = 1; off < CC; off <<= 1) {
            const float od = __shfl_xor(d, off);
            const int   om = __shfl_xor(m, off);
            if (od < d || (od == d && om < m)) { d = od; m = om; }
        }
        bm[i] = m;
    }

    // Epilogue: each point's 32 lanes copy its 64-float value row
    // (1 float2 per lane, coalesced 256B); lane c==0 writes the id.
    #pragma unroll
    for (int i = 0; i < PP; ++i) {
        const float2* vrow = (const float2*)(values + (size_t)bm[i] * DD);
        ((float2*)(out + FEATS_OFF + (size_t)(p0 + i) * DD))[c] = vrow[c];
        if (c == 0) out[IDS_OFF + p0 + i] = (float)bm[i];
    }
}

extern "C" void kernel_launch(void* const* d_in, const int* in_sizes, int n_in,
                              void* d_out, int out_size, void* d_ws, size_t ws_size,
                              hipStream_t stream) {
    const float* pc     = (const float*)d_in[0];
    const float* keys   = (const float*)d_in[1];
    const float* values = (const float*)d_in[2];
    float* out = (float*)d_out;

    dim3 grid(BN / PPB);  // 512 blocks of 512 threads = 2 blocks/CU
    dim3 block(BLK);
    quant_embed_kernel<<<grid, block, 0, stream>>>(pc, keys, values, out);
}